// Round 3
// baseline (319.814 us; speedup 1.0000x reference)
//
#include <hip/hip_runtime.h>

#define NN 50000
#define NE 800000
#define FD 128
#define FDH 64            // FD/2 packed bf16 pairs
#define FA 32
#define NG 128
#define EETOT (NE + NN)
#define NBLK ((NN + 255) / 256)   // 196 scan tiles
#define FEPB 2048                 // fill: edges per chunk
#define FNCH ((EETOT + FEPB - 1) / FEPB)
#define NPXCD 6250                // nodes per XCD-parity bin

typedef __attribute__((ext_vector_type(8))) short short8;
typedef __attribute__((ext_vector_type(4))) float f32x4;

// ---------- bf16 helpers ----------
__device__ __forceinline__ float bfbits(unsigned short u) {
    return __uint_as_float(((unsigned int)u) << 16);
}
__device__ __forceinline__ float bflo(unsigned int p) { return __uint_as_float(p << 16); }
__device__ __forceinline__ float bfhi(unsigned int p) { return __uint_as_float(p & 0xffff0000u); }
__device__ __forceinline__ unsigned short f2bf(float f) {   // RNE
    unsigned int u = __float_as_uint(f);
    unsigned int r = u + 0x7FFFu + ((u >> 16) & 1u);
    return (unsigned short)(r >> 16);
}
__device__ __forceinline__ unsigned int packbf(float a, float b) {
    return (unsigned int)f2bf(a) | ((unsigned int)f2bf(b) << 16);
}

// ---------- inline wave-parallel dtype probes (same decision fn as before) ----------
__device__ __forceinline__ int wave_probe_bf16(const unsigned int* t, int nwords) {
    int lane = threadIdx.x & 63;
    unsigned int wv = (lane < nwords) ? t[lane] : 0u;
    int nzp = (wv != 0u) ? 1 : 0;
    unsigned int e = (wv >> 7) & 0xFFu;
    int hitp = (nzp && e >= 100u && e <= 140u) ? 1 : 0;
    int nz = __popcll(__ballot(nzp));
    int hits = __popcll(__ballot(hitp));
    return (nz < 8) ? 1 : (hits * 4 >= nz * 3);
}
__device__ __forceinline__ int wave_probe_is64(const int* ei) {
    int lane = threadIdx.x & 63;
    int v = (lane < 32) ? ei[2 * lane + 1] : 0;
    return (__ballot(v != 0) == 0ull) ? 1 : 0;
}

// ---------- sentinels ----------
__global__ __launch_bounds__(128) void mark_kernel(float* out, float v) {
    out[threadIdx.x] = v;
}

// ---------- prep: weights + params + zero {degi,tsum,part} ----------
__global__ __launch_bounds__(256) void prep(
        const void* addf, const void* w1, const void* b1, const void* w2,
        const void* b2, const void* fc1w, const void* fc1b, const void* fc2w,
        const void* fc2b, unsigned int* W1t, unsigned int* W2t,
        float* addff, float* b1f, float* b2f, float* fc1wf, float* fc1bf,
        float* fc2wf, float* fc2bf, int* degi, int* tsum, float* part) {
    int b = blockIdx.x;
    if (b < 64) {
        int rel = b * 256 + threadIdx.x;             // [0,16384)
        const void* src = (rel < 8192) ? w1 : w2;
        unsigned int* dst = (rel < 8192) ? W1t : W2t;
        int flag = wave_probe_bf16((const unsigned int*)src, 64);
        int rr = rel & 8191;
        int n = rr >> 6, kk = rr & 63;
        float lo, hi;
        if (flag) {
            const unsigned short* s = (const unsigned short*)src;
            lo = bfbits(s[(2 * kk) * FD + n]);
            hi = bfbits(s[(2 * kk + 1) * FD + n]);
        } else {
            const float* s = (const float*)src;
            lo = s[(2 * kk) * FD + n];
            hi = s[(2 * kk + 1) * FD + n];
        }
        dst[rr] = packbf(lo, hi);
    } else if (b < 163) {
        int i = (b - 64) * 256 + threadIdx.x;        // [0,25344)
        int wb = (b - 64) * 256 + (threadIdx.x & ~63);  // wave base (all bounds 64-aligned)
        const void* src; float* dst; int base; int prnw; int lim;
        if      (wb < 4096)  { src = addf; dst = addff; base = 0;     prnw = 64; lim = 4096;  }
        else if (wb < 4224)  { src = b1;   dst = b1f;   base = 4096;  prnw = 64; lim = 128;   }
        else if (wb < 4352)  { src = b2;   dst = b2f;   base = 4224;  prnw = 64; lim = 128;   }
        else if (wb < 24832) { src = fc1w; dst = fc1wf; base = 4352;  prnw = 64; lim = 20480; }
        else if (wb < 24960) { src = fc1b; dst = fc1bf; base = 24832; prnw = 64; lim = 128;   }
        else if (wb < 25216) { src = fc2w; dst = fc2wf; base = 24960; prnw = 64; lim = 256;   }
        else if (wb < 25280) { src = fc2b; dst = fc2bf; base = 25216; prnw = 1;  lim = 2;     }
        else return;
        int flag = wave_probe_bf16((const unsigned int*)src, prnw);
        int rel = i - base;
        if (rel < lim) {
            if (flag) dst[rel] = bfbits(((const unsigned short*)src)[rel]);
            else      dst[rel] = ((const float*)src)[rel];
        }
    } else {
        int i = (b - 163) * 256 + threadIdx.x;
        if      (i < NN)            degi[i] = 0;
        else if (i < NN + 256)      tsum[i - NN] = 0;
        else if (i < NN + 256 + NG * FD) part[i - NN - 256] = 0.f;
    }
}

// ---------- degree + int32 edge compaction (is64 probed inline) ----------
__global__ __launch_bounds__(256) void deg_kernel(const int* ei, int* deg,
                                                  int* s32, int* d32) {
    int is64 = wave_probe_is64(ei);
    int e = blockIdx.x * 256 + threadIdx.x;
    if (e < NE) {
        int s = is64 ? ei[2 * e] : ei[e];
        int d = is64 ? ei[2 * (NE + e)] : ei[NE + e];
        s32[e] = s;
        d32[e] = d;
        atomicAdd(&deg[d], 1);
    }
}

// ---------- fused scan: tile-scan + lookback + rowstart/cursor/gstart + dinv ----------
__global__ __launch_bounds__(256) void scan_fused(const int* degi, const int* batch,
        int* tsum, float* dinv, int* rowstart, int* cursor, int* gstart) {
    __shared__ int sh[256];
    int b = blockIdx.x, t = threadIdx.x;
    int i = b * 256 + t;
    int d = (i < NN) ? degi[i] : 0;
    if (i < NN) dinv[i] = rsqrtf((float)(d + 1));
    int v = (i < NN) ? d + 1 : 0;
    sh[t] = v;
    __syncthreads();
    for (int off = 1; off < 256; off <<= 1) {
        int a = (t >= off) ? sh[t - off] : 0;
        __syncthreads();
        sh[t] += a;
        __syncthreads();
    }
    int incl = sh[t];
    int total = sh[255];
    // publish own tile sum FIRST (progress guaranteed: deps point downward only)
    if (t == 0) atomicExch(&tsum[b], total);   // total >= 80 > 0 always
    // lookback: lane-parallel sum of all predecessor tile sums
    int pt = 0;
    for (int j = t; j < b; j += 256) {
        int s;
        do { s = atomicAdd(&tsum[j], 0); } while (s == 0);
        pt += s;
    }
    __syncthreads();
    sh[t] = pt;
    __syncthreads();
    for (int off = 128; off >= 1; off >>= 1) {
        if (t < off) sh[t] += sh[t + off];
        __syncthreads();
    }
    int boff = sh[0];
    if (i < NN) {
        int r = boff + incl - v;
        rowstart[i] = r;
        cursor[i]   = r;
    }
    if (i == 0) rowstart[NN] = EETOT;
    if (i < NN) {
        int is64 = (batch[NN - 1] == 0) ? 1 : 0;
        int bc = is64 ? batch[2 * i] : batch[i];
        if (i == 0) {
            for (int g = 0; g <= bc; ++g) gstart[g] = 0;
        } else {
            int bp = is64 ? batch[2 * (i - 1)] : batch[i - 1];
            for (int g = bp + 1; g <= bc; ++g) gstart[g] = i;
        }
        if (i == NN - 1) {
            for (int g = bc + 1; g <= NG; ++g) gstart[g] = NN;
        }
    }
}

// ---------- CSR fill with XCD-affinity dst binning (int32 indices) ----------
__global__ __launch_bounds__(256) void fill_kernel(const int* s32, const int* d32,
        const float* dinv, int* cursor, unsigned int* cv) {
    int chunk = blockIdx.x >> 3;
    int par   = blockIdx.x & 7;
    int base  = chunk * FEPB;
    #pragma unroll
    for (int k = 0; k < FEPB / 256; ++k) {
        int e = base + k * 256 + threadIdx.x;
        if (e >= EETOT) break;
        int s, d;
        if (e < NE) { d = d32[e]; s = -1; }
        else        { s = d = e - NE; }
        if (d / NPXCD != par) continue;
        if (s < 0) s = s32[e];
        int pos = atomicAdd(&cursor[d], 1);
        cv[pos] = (unsigned int)s | ((unsigned int)f2bf(dinv[s] * dinv[d]) << 16);
    }
}

// ---------- MFMA GEMM with optional inline fp32->bf16 A conversion ----------
__global__ __launch_bounds__(256) void gemm_mfma(const void* __restrict__ Av,
        const unsigned int* __restrict__ Wt, unsigned short* __restrict__ C,
        int maybe_f32) {
    int wave = threadIdx.x >> 6;
    int lane = threadIdx.x & 63;
    int quad = lane >> 4;
    int l16  = lane & 15;
    int mbase = blockIdx.x * 64 + wave * 16;
    int ra = mbase + l16;
    if (ra >= NN) ra = NN - 1;
    bool f32in = false;
    if (maybe_f32) f32in = !wave_probe_bf16((const unsigned int*)Av, 64);
    short8 af[4];
    if (!f32in) {
        const uint4* Arow = (const uint4*)((const unsigned int*)Av + (size_t)ra * FDH);
        #pragma unroll
        for (int kk = 0; kk < 4; ++kk) {
            uint4 v = Arow[kk * 4 + quad];
            af[kk] = *(short8*)&v;
        }
    } else {
        const float* Arow = (const float*)Av + (size_t)ra * FD;
        #pragma unroll
        for (int kk = 0; kk < 4; ++kk) {
            const float4* p = (const float4*)(Arow + (kk * 4 + quad) * 8);
            float4 u = p[0], v = p[1];
            uint4 q;
            q.x = packbf(u.x, u.y); q.y = packbf(u.z, u.w);
            q.z = packbf(v.x, v.y); q.w = packbf(v.z, v.w);
            af[kk] = *(short8*)&q;
        }
    }
    #pragma unroll
    for (int nt = 0; nt < 8; ++nt) {
        int n = nt * 16 + l16;
        const uint4* Wrow = (const uint4*)(Wt + (size_t)n * FDH);
        f32x4 acc = {0.f, 0.f, 0.f, 0.f};
        #pragma unroll
        for (int kk = 0; kk < 4; ++kk) {
            uint4 wv = Wrow[kk * 4 + quad];
            short8 bf = *(short8*)&wv;
            acc = __builtin_amdgcn_mfma_f32_16x16x32_bf16(af[kk], bf, acc, 0, 0, 0);
        }
        int row0 = mbase + quad * 4;
        #pragma unroll
        for (int reg = 0; reg < 4; ++reg) {
            int r = row0 + reg;
            if (r < NN) C[(size_t)r * FD + nt * 16 + l16] = f2bf(acc[reg]);
        }
    }
}

// ---------- CSR aggregation (bf16 gather, unroll 8) + bias + relu -> bf16 ----------
__global__ __launch_bounds__(256) void aggregate_kernel(const unsigned int* Hb,
        const unsigned int* cv, const int* rowstart, const float* bias,
        unsigned int* outb) {
    int n = blockIdx.x * 4 + (threadIdx.x >> 6);
    int cp = threadIdx.x & 63;
    if (n >= NN) return;
    int jb = rowstart[n], je = rowstart[n + 1];
    float acc0 = 0.f, acc1 = 0.f;
    int j = jb;
    for (; j + 7 < je; j += 8) {
        unsigned int rr[8], hh[8];
        #pragma unroll
        for (int k = 0; k < 8; ++k) rr[k] = cv[j + k];
        #pragma unroll
        for (int k = 0; k < 8; ++k) hh[k] = Hb[(size_t)(rr[k] & 0xFFFFu) * FDH + cp];
        #pragma unroll
        for (int k = 0; k < 8; ++k) {
            float v = bfbits((unsigned short)(rr[k] >> 16));
            acc0 += v * bflo(hh[k]);
            acc1 += v * bfhi(hh[k]);
        }
    }
    for (; j + 3 < je; j += 4) {
        unsigned int rr[4], hh[4];
        #pragma unroll
        for (int k = 0; k < 4; ++k) rr[k] = cv[j + k];
        #pragma unroll
        for (int k = 0; k < 4; ++k) hh[k] = Hb[(size_t)(rr[k] & 0xFFFFu) * FDH + cp];
        #pragma unroll
        for (int k = 0; k < 4; ++k) {
            float v = bfbits((unsigned short)(rr[k] >> 16));
            acc0 += v * bflo(hh[k]);
            acc1 += v * bfhi(hh[k]);
        }
    }
    for (; j < je; ++j) {
        unsigned int r = cv[j];
        unsigned int h = Hb[(size_t)(r & 0xFFFFu) * FDH + cp];
        float v = bfbits((unsigned short)(r >> 16));
        acc0 += v * bflo(h);
        acc1 += v * bfhi(h);
    }
    acc0 = fmaxf(acc0 + bias[2 * cp], 0.f);
    acc1 = fmaxf(acc1 + bias[2 * cp + 1], 0.f);
    outb[(size_t)n * FDH + cp] = packbf(acc0, acc1);
}

// ---------- layer-2 aggregate + relu + fused mean-pool partials (no H2 write) ----------
__global__ __launch_bounds__(256) void agg_pool(const unsigned int* Hb,
        const unsigned int* cv, const int* rowstart, const float* bias,
        const int* batch, float* part) {
    int w = threadIdx.x >> 6, cp = threadIdx.x & 63;
    int n = blockIdx.x * 4 + w;          // grid = NN/4 exactly
    int is64 = (batch[NN - 1] == 0) ? 1 : 0;
    __shared__ float pp[4][FD];
    __shared__ int gg[4];
    float acc0 = 0.f, acc1 = 0.f;
    int jb = rowstart[n], je = rowstart[n + 1];
    int j = jb;
    for (; j + 7 < je; j += 8) {
        unsigned int rr[8], hh[8];
        #pragma unroll
        for (int k = 0; k < 8; ++k) rr[k] = cv[j + k];
        #pragma unroll
        for (int k = 0; k < 8; ++k) hh[k] = Hb[(size_t)(rr[k] & 0xFFFFu) * FDH + cp];
        #pragma unroll
        for (int k = 0; k < 8; ++k) {
            float v = bfbits((unsigned short)(rr[k] >> 16));
            acc0 += v * bflo(hh[k]);
            acc1 += v * bfhi(hh[k]);
        }
    }
    for (; j + 3 < je; j += 4) {
        unsigned int rr[4], hh[4];
        #pragma unroll
        for (int k = 0; k < 4; ++k) rr[k] = cv[j + k];
        #pragma unroll
        for (int k = 0; k < 4; ++k) hh[k] = Hb[(size_t)(rr[k] & 0xFFFFu) * FDH + cp];
        #pragma unroll
        for (int k = 0; k < 4; ++k) {
            float v = bfbits((unsigned short)(rr[k] >> 16));
            acc0 += v * bflo(hh[k]);
            acc1 += v * bfhi(hh[k]);
        }
    }
    for (; j < je; ++j) {
        unsigned int r = cv[j];
        unsigned int h = Hb[(size_t)(r & 0xFFFFu) * FDH + cp];
        float v = bfbits((unsigned short)(r >> 16));
        acc0 += v * bflo(h);
        acc1 += v * bfhi(h);
    }
    acc0 = fmaxf(acc0 + bias[2 * cp], 0.f);
    acc1 = fmaxf(acc1 + bias[2 * cp + 1], 0.f);
    pp[w][2 * cp]     = acc0;
    pp[w][2 * cp + 1] = acc1;
    if (cp == 0) gg[w] = is64 ? batch[2 * n] : batch[n];
    __syncthreads();
    bool allsame = (gg[0] == gg[1]) && (gg[1] == gg[2]) && (gg[2] == gg[3]);
    if (allsame) {
        if (w == 0) {
            float s0 = pp[0][2 * cp] + pp[1][2 * cp] + pp[2][2 * cp] + pp[3][2 * cp];
            float s1 = pp[0][2 * cp + 1] + pp[1][2 * cp + 1]
                     + pp[2][2 * cp + 1] + pp[3][2 * cp + 1];
            atomicAdd(&part[(size_t)gg[0] * FD + 2 * cp], s0);
            atomicAdd(&part[(size_t)gg[0] * FD + 2 * cp + 1], s1);
        }
    } else {
        atomicAdd(&part[(size_t)gg[w] * FD + 2 * cp], acc0);
        atomicAdd(&part[(size_t)gg[w] * FD + 2 * cp + 1], acc1);
    }
}

// ---------- head: mean + MLP (part is 64KB, L2-hot) ----------
__global__ __launch_bounds__(128) void head_kernel(const float* part, const int* gstart,
        const float* addf, const float* fc1w, const float* fc1b,
        const float* fc2w, const float* fc2b, const unsigned int* x, void* outp) {
    int g = blockIdx.x;
    int t = threadIdx.x;
    __shared__ float z[FD + FA];
    __shared__ float h[FD];
    int obf = wave_probe_bf16(x, 64);
    float cnt = (float)(gstart[g + 1] - gstart[g]);
    if (cnt < 1.0f) cnt = 1.0f;
    z[t] = part[(size_t)g * FD + t] / cnt;
    if (t < FA) z[FD + t] = addf[g * FA + t];
    __syncthreads();
    float acc = fc1b[t];
    #pragma unroll 4
    for (int k = 0; k < FD + FA; ++k)
        acc += z[k] * fc1w[k * FD + t];
    h[t] = fmaxf(acc, 0.f);
    __syncthreads();
    if (t < 2) {
        float o = fc2b[t];
        for (int j = 0; j < FD; ++j) o += h[j] * fc2w[j * 2 + t];
        if (obf) ((unsigned short*)outp)[g * 2 + t] = f2bf(o);
        else     ((float*)outp)[g * 2 + t] = o;
    }
}

extern "C" void kernel_launch(void* const* d_in, const int* in_sizes, int n_in,
                              void* d_out, int out_size, void* d_ws, size_t ws_size,
                              hipStream_t stream) {
    (void)out_size;

    if (n_in != 12) {
        hipLaunchKernelGGL(mark_kernel, dim3(1), dim3(128), 0, stream,
                           (float*)d_out, 2000.0f);
        return;
    }
    const int exp_sizes[12] = {6400000, 1600000, 50000, 4096, 16384, 128,
                               16384, 128, 20480, 128, 256, 2};
    for (int i = 0; i < 12; ++i) {
        if (in_sizes[i] != exp_sizes[i]) {
            hipLaunchKernelGGL(mark_kernel, dim3(1), dim3(128), 0, stream,
                               (float*)d_out, 3000.0f + 100.0f * i);
            return;
        }
    }

    size_t off = 0;
    char* base = (char*)d_ws;
#define WSALLOC(ptr, type, nbytes) \
    type* ptr = (type*)(base + off); off += (((size_t)(nbytes)) + 255) & ~(size_t)255;
    WSALLOC(bufA,  unsigned int, (size_t)NN * FDH * 4)
    WSALLOC(bufB,  unsigned int, (size_t)NN * FDH * 4)
    WSALLOC(dinv,  float, (size_t)NN * 4)
    WSALLOC(degi,  int,   (size_t)NN * 4)
    WSALLOC(rowst, int,   (size_t)(NN + 1) * 4)
    WSALLOC(cursor,int,   (size_t)NN * 4)
    WSALLOC(tsum,  int,   256 * 4)
    WSALLOC(cv,    unsigned int, (size_t)EETOT * 4)
    WSALLOC(gstart,int,   (size_t)(NG + 1) * 4)
    WSALLOC(part,  float, (size_t)NG * FD * 4)
    WSALLOC(s32,   int,   (size_t)NE * 4)
    WSALLOC(d32,   int,   (size_t)NE * 4)
    WSALLOC(W1t,   unsigned int, (size_t)FD * FDH * 4)
    WSALLOC(W2t,   unsigned int, (size_t)FD * FDH * 4)
    WSALLOC(b1f,   float, FD * 4)
    WSALLOC(b2f,   float, FD * 4)
    WSALLOC(addff, float, (size_t)NG * FA * 4)
    WSALLOC(fc1wf, float, (size_t)(FD + FA) * FD * 4)
    WSALLOC(fc1bf, float, FD * 4)
    WSALLOC(fc2wf, float, FD * 2 * 4)
    WSALLOC(fc2bf, float, 2 * 4)
#undef WSALLOC
    if (ws_size < off) {
        hipLaunchKernelGGL(mark_kernel, dim3(1), dim3(128), 0, stream,
                           (float*)d_out, 1000.0f);
        return;
    }

    const int* ei    = (const int*)d_in[1];
    const int* batch = (const int*)d_in[2];

    // prep grid: 64 (W1/W2) + 99 (small tensors) + 261 (zero 66640 words)
    hipLaunchKernelGGL(prep, dim3(424), dim3(256), 0, stream,
                       d_in[3], d_in[4], d_in[5], d_in[6], d_in[7],
                       d_in[8], d_in[9], d_in[10], d_in[11],
                       W1t, W2t, addff, b1f, b2f, fc1wf, fc1bf,
                       fc2wf, fc2bf, degi, tsum, part);

    hipLaunchKernelGGL(deg_kernel, dim3((NE + 255) / 256), dim3(256), 0, stream,
                       ei, degi, s32, d32);
    hipLaunchKernelGGL(scan_fused, dim3(NBLK), dim3(256), 0, stream,
                       degi, batch, tsum, dinv, rowst, cursor, gstart);
    hipLaunchKernelGGL(fill_kernel, dim3(FNCH * 8), dim3(256), 0, stream,
                       s32, d32, dinv, cursor, cv);

    hipLaunchKernelGGL(gemm_mfma, dim3((NN + 63) / 64), dim3(256), 0, stream,
                       d_in[0], W1t, (unsigned short*)bufA, 1);
    hipLaunchKernelGGL(aggregate_kernel, dim3((NN + 3) / 4), dim3(256), 0, stream,
                       bufA, cv, rowst, b1f, bufB);
    hipLaunchKernelGGL(gemm_mfma, dim3((NN + 63) / 64), dim3(256), 0, stream,
                       bufB, W2t, (unsigned short*)bufA, 0);
    hipLaunchKernelGGL(agg_pool, dim3(NN / 4), dim3(256), 0, stream,
                       bufA, cv, rowst, b2f, batch, part);

    hipLaunchKernelGGL(head_kernel, dim3(NG), dim3(128), 0, stream,
                       part, gstart, addff, fc1wf, fc1bf, fc2wf, fc2bf,
                       (const unsigned int*)d_in[0], d_out);
}